// Round 2
// baseline (3594.885 us; speedup 1.0000x reference)
//
#include <hip/hip_runtime.h>
#include <stdint.h>

#define NB 8
#define NPTS 4096
#define NPOINT 1024
#define NSAMPLE 32
#define FCH 64
#define HID 128
#define CAP 320

// d2 computed with EXACT numpy rounding/order: ((dx*dx + dy*dy) + dz*dz),
// no FMA contraction (FPS argmax + radius selection must match ref bitwise).
__device__ __forceinline__ float d2_exact(float ax, float ay, float az,
                                          float bx, float by, float bz) {
  float dx = ax - bx, dy = ay - by, dz = az - bz;
  return __fadd_rn(__fadd_rn(__fmul_rn(dx, dx), __fmul_rn(dy, dy)),
                   __fmul_rn(dz, dz));
}

// ---------------------------------------------------------------- FPS
// 8 blocks x 256 threads (4 waves = 1 wave/SIMD). 16 pts/thread in regs.
// Argmax fused into the min-dist update loop. Packed key (f32<<32)|~idx:
// max -> max dist, ties -> lowest index (matches np.argmax).
__global__ __launch_bounds__(256) void fps_kernel(const float* __restrict__ xyz,
                                                  float* __restrict__ newxyz) {
  __shared__ float xs[NPTS], ys[NPTS], zs[NPTS];
  __shared__ unsigned long long wk[2][4];
  const int b = blockIdx.x;
  const int t = threadIdx.x;
  const float* src = xyz + (size_t)b * NPTS * 3;
  for (int j = t; j < NPTS * 3; j += 256) {
    float v = src[j];
    int p = j / 3;
    int c = j - p * 3;
    if (c == 0) xs[p] = v;
    else if (c == 1) ys[p] = v;
    else zs[p] = v;
  }
  __syncthreads();
  const int base = t * 16;
  float px[16], py[16], pz[16], dist[16];
  const float cx0 = xs[0], cy0 = ys[0], cz0 = zs[0];
  float bv = -INFINITY;
  int br = 0;
#pragma unroll
  for (int r = 0; r < 16; ++r) {
    px[r] = xs[base + r]; py[r] = ys[base + r]; pz[r] = zs[base + r];
    dist[r] = d2_exact(px[r], py[r], pz[r], cx0, cy0, cz0);
    bool c = dist[r] > bv;   // strict > keeps lowest r (idx) on ties
    bv = c ? dist[r] : bv;
    br = c ? r : br;
  }
  if (t == 0) {
    float* o = newxyz + (size_t)b * NPOINT * 3;
    o[0] = cx0; o[1] = cy0; o[2] = cz0;
  }
  for (int it = 1; it < NPOINT; ++it) {
    unsigned long long key = ((unsigned long long)__float_as_uint(bv) << 32) |
                             (unsigned int)(~(base + br));
#pragma unroll
    for (int o = 32; o > 0; o >>= 1) {
      unsigned long long other = __shfl_xor(key, o, 64);
      if (other > key) key = other;
    }
    const int par = it & 1;
    if ((t & 63) == 0) wk[par][t >> 6] = key;
    __syncthreads();  // parity double-buffer -> single barrier/iter is safe
    unsigned long long gk = wk[par][0];
#pragma unroll
    for (int w = 1; w < 4; ++w) {
      unsigned long long o2 = wk[par][w];
      if (o2 > gk) gk = o2;
    }
    const int far = (int)(~(unsigned int)gk) & (NPTS - 1);
    const float ncx = xs[far], ncy = ys[far], ncz = zs[far];
    if (t == 0) {
      float* o = newxyz + ((size_t)b * NPOINT + it) * 3;
      o[0] = ncx; o[1] = ncy; o[2] = ncz;
    }
    bv = -INFINITY;
    br = 0;
#pragma unroll
    for (int r = 0; r < 16; ++r) {
      float d = d2_exact(px[r], py[r], pz[r], ncx, ncy, ncz);
      float nd = fminf(dist[r], d);
      dist[r] = nd;
      bool c = nd > bv;
      bv = c ? nd : bv;
      br = c ? r : br;
    }
  }
}

// ------------------------------------------------------------- neighbor sel
__global__ __launch_bounds__(256) void knn_kernel(const float* __restrict__ xyz,
                                                  const float* __restrict__ newxyz,
                                                  int* __restrict__ gidx) {
  __shared__ unsigned long long cand[4][CAP];
  const int wv = threadIdx.x >> 6;
  const int lane = threadIdx.x & 63;
  const int g = blockIdx.x * 4 + wv;
  const int b = g >> 10;
  const float* src = xyz + (size_t)b * NPTS * 3;
  const float cx = newxyz[g * 3 + 0];
  const float cy = newxyz[g * 3 + 1];
  const float cz = newxyz[g * 3 + 2];
  const float r2 = 0.0225f;  // np float32(RADIUS**2)
  int cnt = 0;
  for (int j0 = 0; j0 < NPTS; j0 += 64) {
    const int p = j0 + lane;
    const float* pp = src + p * 3;
    float d2 = d2_exact(pp[0], pp[1], pp[2], cx, cy, cz);
    bool inr = (d2 <= r2);
    unsigned long long mask = __ballot(inr);
    if (inr) {
      int pos = cnt + __popcll(mask & ((1ull << lane) - 1ull));
      if (pos < CAP)
        cand[wv][pos] =
            ((unsigned long long)__float_as_uint(d2) << 32) | (unsigned int)p;
    }
    cnt += __popcll(mask);
  }
  int C = cnt < CAP ? cnt : CAP;
  int* out = gidx + g * NSAMPLE;
  for (int tt = lane; tt < C; tt += 64) {
    unsigned long long kt = cand[wv][tt];
    int rank = 0;
    for (int u = 0; u < C; ++u) rank += (cand[wv][u] < kt) ? 1 : 0;
    if (rank < NSAMPLE) out[rank] = (int)(kt & 0xffffffffu);
  }
  if (C < NSAMPLE) {  // boundary query: fill with lowest-index outside-radius
    const float* pp = src + lane * 3;
    float d2 = d2_exact(pp[0], pp[1], pp[2], cx, cy, cz);
    bool outr = !(d2 <= r2);
    unsigned long long mask = __ballot(outr);
    if (outr) {
      int pos = __popcll(mask & ((1ull << lane) - 1ull));
      if (pos < NSAMPLE - C) out[C + pos] = lane;
    }
  }
}

// ---------------------------------------------------------------- MLP
// One block (256 thr) per query. Thread tile = 4 samples x 4 channels.
// W staged global->LDS in 32-row chunks (16KB), read via wave-broadcast
// ds_read_b128 (2-way dup = free). w_in never materialized:
// (f'-fm)@W = f'@W - fm@W, dxyz@W1w[0:3] folded into bias.
template <int K, int KW, int LDA>
__device__ __forceinline__ void gemm_chunks(const float* __restrict__ Abase,
                                            int s0,
                                            const float* __restrict__ Wg,
                                            float (*Wc)[HID], int c0,
                                            float acc[4][4]) {
  const int t = threadIdx.x;
  for (int kb = 0; kb < K; kb += 32) {
    const int rows = (K - kb < 32) ? (K - kb) : 32;      // multiple of 4
    const int srcRows = (KW - kb < rows) ? (KW - kb) : rows;
    const int totq = rows * 32, srcq = srcRows * 32;
    const float4* wsrc = (const float4*)(Wg + (size_t)kb * HID);
    float4* wdst = (float4*)(&Wc[0][0]);
    __syncthreads();
    for (int q = t; q < totq; q += 256) {
      float4 v = make_float4(0.f, 0.f, 0.f, 0.f);
      if (q < srcq) v = wsrc[q];
      wdst[q] = v;
    }
    __syncthreads();
    const float* a0 = Abase + (size_t)(s0 + 0) * LDA + kb;
    const float* a1 = Abase + (size_t)(s0 + 1) * LDA + kb;
    const float* a2 = Abase + (size_t)(s0 + 2) * LDA + kb;
    const float* a3 = Abase + (size_t)(s0 + 3) * LDA + kb;
    for (int k = 0; k < rows; k += 4) {
      float4 A0 = *(const float4*)(a0 + k);
      float4 A1 = *(const float4*)(a1 + k);
      float4 A2 = *(const float4*)(a2 + k);
      float4 A3 = *(const float4*)(a3 + k);
#pragma unroll
      for (int kk = 0; kk < 4; ++kk) {
        float4 w = *(const float4*)(&Wc[k + kk][c0]);
        float e0 = (&A0.x)[kk], e1 = (&A1.x)[kk], e2 = (&A2.x)[kk], e3 = (&A3.x)[kk];
        acc[0][0] += e0 * w.x; acc[0][1] += e0 * w.y; acc[0][2] += e0 * w.z; acc[0][3] += e0 * w.w;
        acc[1][0] += e1 * w.x; acc[1][1] += e1 * w.y; acc[1][2] += e1 * w.z; acc[1][3] += e1 * w.w;
        acc[2][0] += e2 * w.x; acc[2][1] += e2 * w.y; acc[2][2] += e2 * w.z; acc[2][3] += e2 * w.w;
        acc[3][0] += e3 * w.x; acc[3][1] += e3 * w.y; acc[3][2] += e3 * w.z; acc[3][3] += e3 * w.w;
      }
    }
  }
}

// G3 variant: also accumulates corr[j] = sum_k fm[k]*W[k][c0+j]
__device__ __forceinline__ void gemm_chunks_corr(const float* __restrict__ Abase,
                                                 int s0,
                                                 const float* __restrict__ Wg,
                                                 float (*Wc)[HID], int c0,
                                                 const float* __restrict__ fm,
                                                 float acc[4][4], float corr[4]) {
  const int t = threadIdx.x;
  for (int kb = 0; kb < HID; kb += 32) {
    const float4* wsrc = (const float4*)(Wg + (size_t)kb * HID);
    float4* wdst = (float4*)(&Wc[0][0]);
    __syncthreads();
    for (int q = t; q < 32 * 32; q += 256) wdst[q] = wsrc[q];
    __syncthreads();
    const float* a0 = Abase + (size_t)(s0 + 0) * HID + kb;
    const float* a1 = Abase + (size_t)(s0 + 1) * HID + kb;
    const float* a2 = Abase + (size_t)(s0 + 2) * HID + kb;
    const float* a3 = Abase + (size_t)(s0 + 3) * HID + kb;
    for (int k = 0; k < 32; k += 4) {
      float4 A0 = *(const float4*)(a0 + k);
      float4 A1 = *(const float4*)(a1 + k);
      float4 A2 = *(const float4*)(a2 + k);
      float4 A3 = *(const float4*)(a3 + k);
      float4 FM = *(const float4*)(fm + kb + k);
#pragma unroll
      for (int kk = 0; kk < 4; ++kk) {
        float4 w = *(const float4*)(&Wc[k + kk][c0]);
        float e0 = (&A0.x)[kk], e1 = (&A1.x)[kk], e2 = (&A2.x)[kk], e3 = (&A3.x)[kk];
        float cf = (&FM.x)[kk];
        acc[0][0] += e0 * w.x; acc[0][1] += e0 * w.y; acc[0][2] += e0 * w.z; acc[0][3] += e0 * w.w;
        acc[1][0] += e1 * w.x; acc[1][1] += e1 * w.y; acc[1][2] += e1 * w.z; acc[1][3] += e1 * w.w;
        acc[2][0] += e2 * w.x; acc[2][1] += e2 * w.y; acc[2][2] += e2 * w.z; acc[2][3] += e2 * w.w;
        acc[3][0] += e3 * w.x; acc[3][1] += e3 * w.y; acc[3][2] += e3 * w.z; acc[3][3] += e3 * w.w;
        corr[0] += cf * w.x; corr[1] += cf * w.y; corr[2] += cf * w.z; corr[3] += cf * w.w;
      }
    }
  }
}

__global__ __launch_bounds__(256) void mlp_kernel(
    const float* __restrict__ xyz, const float* __restrict__ feats,
    const float* __restrict__ W1f, const float* __restrict__ b1f,
    const float* __restrict__ W2f, const float* __restrict__ b2f,
    const float* __restrict__ W1w, const float* __restrict__ b1w,
    const float* __restrict__ W2w, const float* __restrict__ b2w,
    const int* __restrict__ gidx, const float* __restrict__ newxyz,
    float* __restrict__ fout) {
  __shared__ float fin[32][68];    // dxyz 0..2, feats 3..66, pad 67=0 (8.5KB)
  __shared__ float bufA[32][HID];  // h1 then h2 (16KB)
  __shared__ float fp[32][HID];    // f_prime (16KB)
  __shared__ float fm[HID];
  __shared__ float Wc[32][HID];    // W chunk (16KB)
  __shared__ int sidx[32];
  // red[8][HID] overlaid onto fin (fin dead by G4 epilogue)
  float* redp = &fin[0][0];

  const int g = blockIdx.x;
  const int b = g >> 10;
  const int t = threadIdx.x;

  if (t < 32) sidx[t] = gidx[g * NSAMPLE + t];
  const float cx = newxyz[g * 3 + 0];
  const float cy = newxyz[g * 3 + 1];
  const float cz = newxyz[g * 3 + 2];
  __syncthreads();
  if (t < 32) {
    const float* pp = xyz + ((size_t)b * NPTS + sidx[t]) * 3;
    fin[t][0] = pp[0] - cx;
    fin[t][1] = pp[1] - cy;
    fin[t][2] = pp[2] - cz;
    fin[t][67] = 0.f;
  }
  for (int e = t; e < 32 * FCH; e += 256) {
    int s = e >> 6;
    int c = e & 63;
    fin[s][3 + c] = feats[((size_t)b * NPTS + sidx[s]) * FCH + c];
  }
  // (gemm's staging barrier publishes fin)

  const int s0 = (t >> 5) * 4;
  const int c0 = (t & 31) * 4;
  float acc[4][4];

  // G1: relu(f_in @ W1f + b1f) -> bufA
  {
    float4 bv = *(const float4*)(b1f + c0);
#pragma unroll
    for (int i = 0; i < 4; ++i) { acc[i][0] = bv.x; acc[i][1] = bv.y; acc[i][2] = bv.z; acc[i][3] = bv.w; }
  }
  gemm_chunks<68, 67, 68>(&fin[0][0], s0, W1f, Wc, c0, acc);
#pragma unroll
  for (int i = 0; i < 4; ++i)
#pragma unroll
    for (int j = 0; j < 4; ++j) bufA[s0 + i][c0 + j] = fmaxf(acc[i][j], 0.f);

  // G2: relu(h1 @ W2f + b2f) -> fp (LDS + regs)
  {
    float4 bv = *(const float4*)(b2f + c0);
#pragma unroll
    for (int i = 0; i < 4; ++i) { acc[i][0] = bv.x; acc[i][1] = bv.y; acc[i][2] = bv.z; acc[i][3] = bv.w; }
  }
  gemm_chunks<128, 128, 128>(&bufA[0][0], s0, W2f, Wc, c0, acc);
  float fpreg[4][4];
#pragma unroll
  for (int i = 0; i < 4; ++i)
#pragma unroll
    for (int j = 0; j < 4; ++j) {
      fpreg[i][j] = fmaxf(acc[i][j], 0.f);
      fp[s0 + i][c0 + j] = fpreg[i][j];
    }
  __syncthreads();

  // mean over samples
  if (t < HID) {
    float s = 0.f;
#pragma unroll 8
    for (int i = 0; i < 32; ++i) s += fp[i][t];
    fm[t] = s * (1.0f / 32.0f);
  }
  // (G3 staging barrier publishes fm)

  // G3: relu( fp@W1w[3:] + (b1w + dxyz@W1w[0:3] - fm@W1w[3:]) ) -> bufA
  float corr[4] = {0.f, 0.f, 0.f, 0.f};
  {
    float4 bv = *(const float4*)(b1w + c0);
    float4 w0 = *(const float4*)(W1w + 0 * HID + c0);
    float4 w1 = *(const float4*)(W1w + 1 * HID + c0);
    float4 w2 = *(const float4*)(W1w + 2 * HID + c0);
#pragma unroll
    for (int i = 0; i < 4; ++i) {
      float dx = fin[s0 + i][0], dy = fin[s0 + i][1], dz = fin[s0 + i][2];
      acc[i][0] = bv.x + dx * w0.x + dy * w1.x + dz * w2.x;
      acc[i][1] = bv.y + dx * w0.y + dy * w1.y + dz * w2.y;
      acc[i][2] = bv.z + dx * w0.z + dy * w1.z + dz * w2.z;
      acc[i][3] = bv.w + dx * w0.w + dy * w1.w + dz * w2.w;
    }
  }
  gemm_chunks_corr(&fp[0][0], s0, W1w + 3 * HID, Wc, c0, fm, acc, corr);
#pragma unroll
  for (int i = 0; i < 4; ++i)
#pragma unroll
    for (int j = 0; j < 4; ++j) bufA[s0 + i][c0 + j] = fmaxf(acc[i][j] - corr[j], 0.f);

  // G4: alpha = sigmoid(h2 @ W2w + b2w); f_out = sum_s alpha*f'
  {
    float4 bv = *(const float4*)(b2w + c0);
#pragma unroll
    for (int i = 0; i < 4; ++i) { acc[i][0] = bv.x; acc[i][1] = bv.y; acc[i][2] = bv.z; acc[i][3] = bv.w; }
  }
  gemm_chunks<128, 128, 128>(&bufA[0][0], s0, W2w, Wc, c0, acc);
  {
    float part[4] = {0.f, 0.f, 0.f, 0.f};
#pragma unroll
    for (int i = 0; i < 4; ++i)
#pragma unroll
      for (int j = 0; j < 4; ++j) {
        float al = 1.0f / (1.0f + __expf(-acc[i][j]));
        part[j] += al * fpreg[i][j];
      }
    __syncthreads();  // fin (incl. dxyz) fully dead -> reuse as red
    redp[(t >> 5) * HID + c0 + 0] = part[0];
    redp[(t >> 5) * HID + c0 + 1] = part[1];
    redp[(t >> 5) * HID + c0 + 2] = part[2];
    redp[(t >> 5) * HID + c0 + 3] = part[3];
  }
  __syncthreads();
  if (t < HID) {
    float s = 0.f;
#pragma unroll
    for (int w = 0; w < 8; ++w) s += redp[w * HID + t];
    fout[(size_t)g * HID + t] = s;
  }
}

extern "C" void kernel_launch(void* const* d_in, const int* in_sizes, int n_in,
                              void* d_out, int out_size, void* d_ws, size_t ws_size,
                              hipStream_t stream) {
  const float* xyz = (const float*)d_in[0];
  const float* feats = (const float*)d_in[1];
  const float* W1f = (const float*)d_in[2];
  const float* b1f = (const float*)d_in[3];
  const float* W2f = (const float*)d_in[4];
  const float* b2f = (const float*)d_in[5];
  const float* W1w = (const float*)d_in[6];
  const float* b1w = (const float*)d_in[7];
  const float* W2w = (const float*)d_in[8];
  const float* b2w = (const float*)d_in[9];

  float* newxyz = (float*)d_out;                          // (8,1024,3)
  float* fout = (float*)d_out + (size_t)NB * NPOINT * 3;  // (8,1024,128)
  int* gidx = (int*)d_ws;                                 // (8192,32)

  fps_kernel<<<NB, 256, 0, stream>>>(xyz, newxyz);
  knn_kernel<<<NB * NPOINT / 4, 256, 0, stream>>>(xyz, newxyz, gidx);
  mlp_kernel<<<NB * NPOINT, 256, 0, stream>>>(xyz, feats, W1f, b1f, W2f, b2f,
                                              W1w, b1w, W2w, b2w, gidx, newxyz,
                                              fout);
}

// Round 3
// 1205.456 us; speedup vs baseline: 2.9822x; 2.9822x over previous
//
#include <hip/hip_runtime.h>
#include <stdint.h>

#define NB 8
#define NPTS 4096
#define NPOINT 1024
#define NSAMPLE 32
#define FCH 64
#define HID 128
#define CAP 320

// d2 computed with EXACT numpy rounding/order: ((dx*dx + dy*dy) + dz*dz),
// no FMA contraction (FPS argmax + radius selection must match ref bitwise).
__device__ __forceinline__ float d2_exact(float ax, float ay, float az,
                                          float bx, float by, float bz) {
  float dx = ax - bx, dy = ay - by, dz = az - bz;
  return __fadd_rn(__fadd_rn(__fmul_rn(dx, dx), __fmul_rn(dy, dy)),
                   __fmul_rn(dz, dz));
}

// DPP f32 max step (identity 0 is valid: all dists >= 0). VALU pipe, short
// latency — replaces the ds_swizzle u64 butterfly.
#define DPPMAX(v, ctrl)                                                     \
  v = fmaxf(v, __int_as_float(__builtin_amdgcn_update_dpp(                  \
                 0, __float_as_int(v), ctrl, 0xf, 0xf, true)))

// ---------------------------------------------------------------- FPS
// 8 blocks x 256 threads (4 waves). 16 pts/thread in regs; pts as float4 in
// LDS; centroids buffered in LDS (NO per-iter global store -> no vmcnt(0)
// drain at the barrier). Wave argmax: 6 DPP max steps + ballot/ffs (lane
// order == index order, so lowest set lane == lowest index, matching
// np.argmax first-occurrence semantics).
__global__ __launch_bounds__(256) void fps_kernel(const float* __restrict__ xyz,
                                                  float* __restrict__ newxyz) {
  __shared__ float4 pts[NPTS];           // 64 KB
  __shared__ float outbuf[NPOINT * 3];   // 12 KB
  __shared__ float4 wkd4[2];             // per-wave max dist (parity dbuf)
  __shared__ int4 wki4[2];               // per-wave argmax idx
  const int b = blockIdx.x;
  const int t = threadIdx.x;
  const int wid = t >> 6;
  const float* src = xyz + (size_t)b * NPTS * 3;
  for (int j = t; j < NPTS; j += 256) {
    const float* p = src + 3 * j;
    pts[j] = make_float4(p[0], p[1], p[2], 0.f);
  }
  __syncthreads();
  const int base = t * 16;
  float px[16], py[16], pz[16], dist[16];
  const float4 c0 = pts[0];
  float bv = -INFINITY;
  int br = 0;
#pragma unroll
  for (int r = 0; r < 16; ++r) {
    float4 p = pts[base + r];
    px[r] = p.x; py[r] = p.y; pz[r] = p.z;
    dist[r] = d2_exact(px[r], py[r], pz[r], c0.x, c0.y, c0.z);
    bool c = dist[r] > bv;  // strict > keeps lowest r (idx) on ties
    bv = c ? dist[r] : bv;
    br = c ? r : br;
  }
  if (t == 0) {
    outbuf[0] = c0.x; outbuf[1] = c0.y; outbuf[2] = c0.z;
  }
  for (int it = 1; it < NPOINT; ++it) {
    // in-wave max (DPP): after shr1/2/4/8 + bcast15 + bcast31, lane 63 = max
    float wm = bv;
    DPPMAX(wm, 0x111); DPPMAX(wm, 0x112); DPPMAX(wm, 0x114); DPPMAX(wm, 0x118);
    DPPMAX(wm, 0x142); DPPMAX(wm, 0x143);
    float gmaxw = __int_as_float(__builtin_amdgcn_readlane(__float_as_int(wm), 63));
    unsigned long long m = __ballot(bv == gmaxw);
    int lead = __ffsll((long long)m) - 1;  // lowest lane == lowest index
    int widx = __builtin_amdgcn_readlane(base + br, lead);
    const int par = it & 1;
    if ((t & 63) == 0) {
      ((float*)&wkd4[par])[wid] = gmaxw;
      ((int*)&wki4[par])[wid] = widx;
    }
    __syncthreads();  // parity double-buffer -> single barrier/iter is safe
    float4 dd = wkd4[par];
    int4 ii = wki4[par];
    float d = dd.x; int fi = ii.x;
    bool c1 = (dd.y > d) || (dd.y == d && ii.y < fi);
    d = c1 ? dd.y : d; fi = c1 ? ii.y : fi;
    bool c2 = (dd.z > d) || (dd.z == d && ii.z < fi);
    d = c2 ? dd.z : d; fi = c2 ? ii.z : fi;
    bool c3 = (dd.w > d) || (dd.w == d && ii.w < fi);
    fi = c3 ? ii.w : fi;
    const float4 cp = pts[fi];
    if (t == 0) {
      outbuf[3 * it + 0] = cp.x;
      outbuf[3 * it + 1] = cp.y;
      outbuf[3 * it + 2] = cp.z;
    }
    bv = -INFINITY;
    br = 0;
#pragma unroll
    for (int r = 0; r < 16; ++r) {
      float dnew = d2_exact(px[r], py[r], pz[r], cp.x, cp.y, cp.z);
      float nd = fminf(dist[r], dnew);
      dist[r] = nd;
      bool c = nd > bv;
      bv = c ? nd : bv;
      br = c ? r : br;
    }
  }
  __syncthreads();
  float* dst = newxyz + (size_t)b * NPOINT * 3;
  for (int j = t; j < NPOINT * 3; j += 256) dst[j] = outbuf[j];
}

// ------------------------------------------------------------- neighbor sel
__global__ __launch_bounds__(256) void knn_kernel(const float* __restrict__ xyz,
                                                  const float* __restrict__ newxyz,
                                                  int* __restrict__ gidx) {
  __shared__ unsigned long long cand[4][CAP];
  const int wv = threadIdx.x >> 6;
  const int lane = threadIdx.x & 63;
  const int g = blockIdx.x * 4 + wv;
  const int b = g >> 10;
  const float* src = xyz + (size_t)b * NPTS * 3;
  const float cx = newxyz[g * 3 + 0];
  const float cy = newxyz[g * 3 + 1];
  const float cz = newxyz[g * 3 + 2];
  const float r2 = 0.0225f;  // np float32(RADIUS**2)
  int cnt = 0;
  for (int j0 = 0; j0 < NPTS; j0 += 64) {
    const int p = j0 + lane;
    const float* pp = src + p * 3;
    float d2 = d2_exact(pp[0], pp[1], pp[2], cx, cy, cz);
    bool inr = (d2 <= r2);
    unsigned long long mask = __ballot(inr);
    if (inr) {
      int pos = cnt + __popcll(mask & ((1ull << lane) - 1ull));
      if (pos < CAP)
        cand[wv][pos] =
            ((unsigned long long)__float_as_uint(d2) << 32) | (unsigned int)p;
    }
    cnt += __popcll(mask);
  }
  int C = cnt < CAP ? cnt : CAP;
  int* out = gidx + g * NSAMPLE;
  for (int tt = lane; tt < C; tt += 64) {
    unsigned long long kt = cand[wv][tt];
    int rank = 0;
    for (int u = 0; u < C; ++u) rank += (cand[wv][u] < kt) ? 1 : 0;
    if (rank < NSAMPLE) out[rank] = (int)(kt & 0xffffffffu);
  }
  if (C < NSAMPLE) {  // boundary query: fill with lowest-index outside-radius
    const float* pp = src + lane * 3;
    float d2 = d2_exact(pp[0], pp[1], pp[2], cx, cy, cz);
    bool outr = !(d2 <= r2);
    unsigned long long mask = __ballot(outr);
    if (outr) {
      int pos = __popcll(mask & ((1ull << lane) - 1ull));
      if (pos < NSAMPLE - C) out[C + pos] = lane;
    }
  }
}

// ---------------------------------------------------------------- MLP
// One block (256 thr) per query. Thread tile = 4 samples x 4 channels.
// W streamed from global (L2-resident; R1-proven — NO LDS round-trip: the
// staging variant spilled at VGPR=256 -> 7.5 GB scratch traffic in R2).
// w_in never materialized: (f'-fm)@W = f'@W - fm@W, dxyz@W1w[0:3] folded
// into the bias.
template <int K>
__device__ __forceinline__ void gemm_tile(const float* __restrict__ a0,
                                          const float* __restrict__ a1,
                                          const float* __restrict__ a2,
                                          const float* __restrict__ a3,
                                          const float* __restrict__ W,
                                          float acc[4][4]) {
  int k = 0;
  for (; k + 4 <= K; k += 4) {
    float4 A0 = *(const float4*)(a0 + k);
    float4 A1 = *(const float4*)(a1 + k);
    float4 A2 = *(const float4*)(a2 + k);
    float4 A3 = *(const float4*)(a3 + k);
#pragma unroll
    for (int kk = 0; kk < 4; ++kk) {
      float4 w = *(const float4*)(W + (size_t)(k + kk) * HID);
      float e0 = (&A0.x)[kk], e1 = (&A1.x)[kk], e2 = (&A2.x)[kk], e3 = (&A3.x)[kk];
      acc[0][0] += e0 * w.x; acc[0][1] += e0 * w.y; acc[0][2] += e0 * w.z; acc[0][3] += e0 * w.w;
      acc[1][0] += e1 * w.x; acc[1][1] += e1 * w.y; acc[1][2] += e1 * w.z; acc[1][3] += e1 * w.w;
      acc[2][0] += e2 * w.x; acc[2][1] += e2 * w.y; acc[2][2] += e2 * w.z; acc[2][3] += e2 * w.w;
      acc[3][0] += e3 * w.x; acc[3][1] += e3 * w.y; acc[3][2] += e3 * w.z; acc[3][3] += e3 * w.w;
    }
  }
  for (; k < K; ++k) {
    float4 w = *(const float4*)(W + (size_t)k * HID);
    float e0 = a0[k], e1 = a1[k], e2 = a2[k], e3 = a3[k];
    acc[0][0] += e0 * w.x; acc[0][1] += e0 * w.y; acc[0][2] += e0 * w.z; acc[0][3] += e0 * w.w;
    acc[1][0] += e1 * w.x; acc[1][1] += e1 * w.y; acc[1][2] += e1 * w.z; acc[1][3] += e1 * w.w;
    acc[2][0] += e2 * w.x; acc[2][1] += e2 * w.y; acc[2][2] += e2 * w.z; acc[2][3] += e2 * w.w;
    acc[3][0] += e3 * w.x; acc[3][1] += e3 * w.y; acc[3][2] += e3 * w.z; acc[3][3] += e3 * w.w;
  }
}

// K=128 variant that also accumulates corr[j] = sum_k fm[k]*W[k][j]
__device__ __forceinline__ void gemm_tile_corr(const float* __restrict__ a0,
                                               const float* __restrict__ a1,
                                               const float* __restrict__ a2,
                                               const float* __restrict__ a3,
                                               const float* __restrict__ W,
                                               const float* __restrict__ fm,
                                               float acc[4][4], float corr[4]) {
  for (int k = 0; k < HID; k += 4) {
    float4 A0 = *(const float4*)(a0 + k);
    float4 A1 = *(const float4*)(a1 + k);
    float4 A2 = *(const float4*)(a2 + k);
    float4 A3 = *(const float4*)(a3 + k);
    float4 FM = *(const float4*)(fm + k);
#pragma unroll
    for (int kk = 0; kk < 4; ++kk) {
      float4 w = *(const float4*)(W + (size_t)(k + kk) * HID);
      float e0 = (&A0.x)[kk], e1 = (&A1.x)[kk], e2 = (&A2.x)[kk], e3 = (&A3.x)[kk];
      float cf = (&FM.x)[kk];
      acc[0][0] += e0 * w.x; acc[0][1] += e0 * w.y; acc[0][2] += e0 * w.z; acc[0][3] += e0 * w.w;
      acc[1][0] += e1 * w.x; acc[1][1] += e1 * w.y; acc[1][2] += e1 * w.z; acc[1][3] += e1 * w.w;
      acc[2][0] += e2 * w.x; acc[2][1] += e2 * w.y; acc[2][2] += e2 * w.z; acc[2][3] += e2 * w.w;
      acc[3][0] += e3 * w.x; acc[3][1] += e3 * w.y; acc[3][2] += e3 * w.z; acc[3][3] += e3 * w.w;
      corr[0] += cf * w.x; corr[1] += cf * w.y; corr[2] += cf * w.z; corr[3] += cf * w.w;
    }
  }
}

__global__ __launch_bounds__(256) void mlp_kernel(
    const float* __restrict__ xyz, const float* __restrict__ feats,
    const float* __restrict__ W1f, const float* __restrict__ b1f,
    const float* __restrict__ W2f, const float* __restrict__ b2f,
    const float* __restrict__ W1w, const float* __restrict__ b1w,
    const float* __restrict__ W2w, const float* __restrict__ b2w,
    const int* __restrict__ gidx, const float* __restrict__ newxyz,
    float* __restrict__ fout) {
  __shared__ float fin[32][68];    // dxyz 0..2, feats 3..66, pad 67=0 (8.5KB)
  __shared__ float bufA[32][HID];  // h1 then h2 (16KB)
  __shared__ float fp[32][HID];    // f_prime (16KB)
  __shared__ float fm[HID];
  __shared__ int sidx[32];
  float* redp = &fin[0][0];  // red[8][HID] overlaid (fin dead by G4 epilogue)

  const int g = blockIdx.x;
  const int b = g >> 10;
  const int t = threadIdx.x;

  if (t < 32) sidx[t] = gidx[g * NSAMPLE + t];
  const float cx = newxyz[g * 3 + 0];
  const float cy = newxyz[g * 3 + 1];
  const float cz = newxyz[g * 3 + 2];
  __syncthreads();
  if (t < 32) {
    const float* pp = xyz + ((size_t)b * NPTS + sidx[t]) * 3;
    fin[t][0] = pp[0] - cx;
    fin[t][1] = pp[1] - cy;
    fin[t][2] = pp[2] - cz;
    fin[t][67] = 0.f;
  }
  for (int e = t; e < 32 * FCH; e += 256) {
    int s = e >> 6;
    int c = e & 63;
    fin[s][3 + c] = feats[((size_t)b * NPTS + sidx[s]) * FCH + c];
  }
  __syncthreads();

  const int s0 = (t >> 5) * 4;
  const int c0 = (t & 31) * 4;
  float acc[4][4];

  // G1: relu(f_in @ W1f + b1f) -> bufA
  {
    float4 bv = *(const float4*)(b1f + c0);
#pragma unroll
    for (int i = 0; i < 4; ++i) { acc[i][0] = bv.x; acc[i][1] = bv.y; acc[i][2] = bv.z; acc[i][3] = bv.w; }
  }
  gemm_tile<67>(fin[s0], fin[s0 + 1], fin[s0 + 2], fin[s0 + 3], W1f + c0, acc);
#pragma unroll
  for (int i = 0; i < 4; ++i)
#pragma unroll
    for (int j = 0; j < 4; ++j) bufA[s0 + i][c0 + j] = fmaxf(acc[i][j], 0.f);
  __syncthreads();

  // G2: relu(h1 @ W2f + b2f) -> fp
  {
    float4 bv = *(const float4*)(b2f + c0);
#pragma unroll
    for (int i = 0; i < 4; ++i) { acc[i][0] = bv.x; acc[i][1] = bv.y; acc[i][2] = bv.z; acc[i][3] = bv.w; }
  }
  gemm_tile<128>(bufA[s0], bufA[s0 + 1], bufA[s0 + 2], bufA[s0 + 3], W2f + c0, acc);
#pragma unroll
  for (int i = 0; i < 4; ++i)
#pragma unroll
    for (int j = 0; j < 4; ++j) fp[s0 + i][c0 + j] = fmaxf(acc[i][j], 0.f);
  __syncthreads();

  // mean over samples
  if (t < HID) {
    float s = 0.f;
#pragma unroll 8
    for (int i = 0; i < 32; ++i) s += fp[i][t];
    fm[t] = s * (1.0f / 32.0f);
  }
  __syncthreads();

  // G3: relu( fp@W1w[3:] + (b1w + dxyz@W1w[0:3]) - fm@W1w[3:] ) -> bufA
  float corr[4] = {0.f, 0.f, 0.f, 0.f};
  {
    float4 bv = *(const float4*)(b1w + c0);
    float4 w0 = *(const float4*)(W1w + 0 * HID + c0);
    float4 w1 = *(const float4*)(W1w + 1 * HID + c0);
    float4 w2 = *(const float4*)(W1w + 2 * HID + c0);
#pragma unroll
    for (int i = 0; i < 4; ++i) {
      float dx = fin[s0 + i][0], dy = fin[s0 + i][1], dz = fin[s0 + i][2];
      acc[i][0] = bv.x + dx * w0.x + dy * w1.x + dz * w2.x;
      acc[i][1] = bv.y + dx * w0.y + dy * w1.y + dz * w2.y;
      acc[i][2] = bv.z + dx * w0.z + dy * w1.z + dz * w2.z;
      acc[i][3] = bv.w + dx * w0.w + dy * w1.w + dz * w2.w;
    }
  }
  gemm_tile_corr(fp[s0], fp[s0 + 1], fp[s0 + 2], fp[s0 + 3],
                 W1w + 3 * HID + c0, fm, acc, corr);
  __syncthreads();  // bufA (h1) reads done before overwrite with h2
#pragma unroll
  for (int i = 0; i < 4; ++i)
#pragma unroll
    for (int j = 0; j < 4; ++j) bufA[s0 + i][c0 + j] = fmaxf(acc[i][j] - corr[j], 0.f);
  __syncthreads();

  // G4: alpha = sigmoid(h2 @ W2w + b2w); f_out = sum_s alpha*f'
  {
    float4 bv = *(const float4*)(b2w + c0);
#pragma unroll
    for (int i = 0; i < 4; ++i) { acc[i][0] = bv.x; acc[i][1] = bv.y; acc[i][2] = bv.z; acc[i][3] = bv.w; }
  }
  gemm_tile<128>(bufA[s0], bufA[s0 + 1], bufA[s0 + 2], bufA[s0 + 3], W2w + c0, acc);
  {
    float part[4] = {0.f, 0.f, 0.f, 0.f};
#pragma unroll
    for (int i = 0; i < 4; ++i)
#pragma unroll
      for (int j = 0; j < 4; ++j) {
        float al = 1.0f / (1.0f + __expf(-acc[i][j]));
        part[j] += al * fp[s0 + i][c0 + j];
      }
    __syncthreads();  // fin (incl. dxyz) fully dead -> reuse as red
    redp[(t >> 5) * HID + c0 + 0] = part[0];
    redp[(t >> 5) * HID + c0 + 1] = part[1];
    redp[(t >> 5) * HID + c0 + 2] = part[2];
    redp[(t >> 5) * HID + c0 + 3] = part[3];
  }
  __syncthreads();
  if (t < HID) {
    float s = 0.f;
#pragma unroll
    for (int w = 0; w < 8; ++w) s += redp[w * HID + t];
    fout[(size_t)g * HID + t] = s;
  }
}

extern "C" void kernel_launch(void* const* d_in, const int* in_sizes, int n_in,
                              void* d_out, int out_size, void* d_ws, size_t ws_size,
                              hipStream_t stream) {
  const float* xyz = (const float*)d_in[0];
  const float* feats = (const float*)d_in[1];
  const float* W1f = (const float*)d_in[2];
  const float* b1f = (const float*)d_in[3];
  const float* W2f = (const float*)d_in[4];
  const float* b2f = (const float*)d_in[5];
  const float* W1w = (const float*)d_in[6];
  const float* b1w = (const float*)d_in[7];
  const float* W2w = (const float*)d_in[8];
  const float* b2w = (const float*)d_in[9];

  float* newxyz = (float*)d_out;                          // (8,1024,3)
  float* fout = (float*)d_out + (size_t)NB * NPOINT * 3;  // (8,1024,128)
  int* gidx = (int*)d_ws;                                 // (8192,32)

  fps_kernel<<<NB, 256, 0, stream>>>(xyz, newxyz);
  knn_kernel<<<NB * NPOINT / 4, 256, 0, stream>>>(xyz, newxyz, gidx);
  mlp_kernel<<<NB * NPOINT, 256, 0, stream>>>(xyz, feats, W1f, b1f, W2f, b2f,
                                              W1w, b1w, W2w, b2w, gidx, newxyz,
                                              fout);
}

// Round 4
// 1139.260 us; speedup vs baseline: 3.1555x; 1.0581x over previous
//
#include <hip/hip_runtime.h>
#include <stdint.h>

#define NB 8
#define NPTS 4096
#define NPOINT 1024
#define NSAMPLE 32
#define FCH 64
#define HID 128
#define CAPW 160  // per-wave candidate capacity (expected ~15/segment)

typedef unsigned long long ull;

// d2 computed with EXACT numpy rounding/order: ((dx*dx + dy*dy) + dz*dz),
// no FMA contraction (FPS argmax + radius selection must match ref bitwise).
__device__ __forceinline__ float d2_exact(float ax, float ay, float az,
                                          float bx, float by, float bz) {
  float dx = ax - bx, dy = ay - by, dz = az - bz;
  return __fadd_rn(__fadd_rn(__fmul_rn(dx, dx), __fmul_rn(dy, dy)),
                   __fmul_rn(dz, dz));
}

// DPP f32 max step (identity 0 valid: dists >= 0). VALU pipe.
#define DPPMAX(v, ctrl)                                                     \
  v = fmaxf(v, __int_as_float(__builtin_amdgcn_update_dpp(                  \
                 0, __float_as_int(v), ctrl, 0xf, 0xf, true)))

// ---------------- shared-memory union (producer 66.4KB / consumer 52.4KB) --
struct ProdS {
  float4 pts[NPTS];      // 64 KB
  float chunk[64 * 3];   // 64-centroid publish buffer
  float4 wkd4[2];        // per-wave max dist (parity dbuf)
  int4 wki4[2];          // per-wave argmax idx
};
struct ConsS {
  float fin[32][68];     // dxyz 0..2, feats 3..66, pad 67
  float bufA[32][HID];   // h1 then h2
  float fp[32][HID];     // f_prime
  float fm[HID];
  ull candseg[4][CAPW];  // per-wave radius candidates
  ull cand2[4 * CAPW];   // compacted
  int sidx[NSAMPLE];
  int scnt[4];
  int tkS;
};
union SMemU {
  ProdS p;
  ConsS c;
};

// ---------------------------------------------------------------- FPS
// (R3-proven body: 256 thr, 16 pts/thread in regs, DPP wave argmax, parity
// LDS exchange.) Publishes centroids to GLOBAL in 64-chunks: flush stores by
// waves 0-2 + __threadfence, barrier, then release-store of progress[b].
__device__ void run_fps(const float* __restrict__ xyz,
                        float* __restrict__ newxyz, int* progress, int b,
                        ProdS& S) {
  const int t = threadIdx.x;
  const int wid = t >> 6;
  const float* src = xyz + (size_t)b * NPTS * 3;
  float* dstb = newxyz + (size_t)b * NPOINT * 3;
  for (int j = t; j < NPTS; j += 256) {
    const float* p = src + 3 * j;
    S.pts[j] = make_float4(p[0], p[1], p[2], 0.f);
  }
  __syncthreads();
  const int base = t * 16;
  float px[16], py[16], pz[16], dist[16];
  const float4 c0 = S.pts[0];
  float bv = -INFINITY;
  int br = 0;
#pragma unroll
  for (int r = 0; r < 16; ++r) {
    float4 p = S.pts[base + r];
    px[r] = p.x; py[r] = p.y; pz[r] = p.z;
    dist[r] = d2_exact(px[r], py[r], pz[r], c0.x, c0.y, c0.z);
    bool c = dist[r] > bv;  // strict > keeps lowest r (idx) on ties
    bv = c ? dist[r] : bv;
    br = c ? r : br;
  }
  if (t == 0) {
    S.chunk[0] = c0.x; S.chunk[1] = c0.y; S.chunk[2] = c0.z;
  }
  for (int it = 1; it < NPOINT; ++it) {
    float wm = bv;
    DPPMAX(wm, 0x111); DPPMAX(wm, 0x112); DPPMAX(wm, 0x114); DPPMAX(wm, 0x118);
    DPPMAX(wm, 0x142); DPPMAX(wm, 0x143);
    float gmaxw =
        __int_as_float(__builtin_amdgcn_readlane(__float_as_int(wm), 63));
    ull m = __ballot(bv == gmaxw);
    int lead = __ffsll((long long)m) - 1;  // lowest lane == lowest index
    int widx = __builtin_amdgcn_readlane(base + br, lead);
    const int par = it & 1;
    if ((t & 63) == 0) {
      ((float*)&S.wkd4[par])[wid] = gmaxw;
      ((int*)&S.wki4[par])[wid] = widx;
    }
    __syncthreads();  // parity double-buffer -> single barrier/iter
    if ((it & 63) == 0) {
      // publish centroids [it-64, it): stores+fence by waves 0-2 (wave-
      // uniform predicate), barrier, release-store of the counter.
      if (t < 192) {
        dstb[(it - 64) * 3 + t] = S.chunk[t];
        __threadfence();
      }
      __syncthreads();
      if (t == 0)
        __hip_atomic_store(&progress[b], it, __ATOMIC_RELEASE,
                           __HIP_MEMORY_SCOPE_AGENT);
    }
    float4 dd = S.wkd4[par];
    int4 ii = S.wki4[par];
    float d = dd.x; int fi = ii.x;
    bool c1 = (dd.y > d) || (dd.y == d && ii.y < fi);
    d = c1 ? dd.y : d; fi = c1 ? ii.y : fi;
    bool c2 = (dd.z > d) || (dd.z == d && ii.z < fi);
    d = c2 ? dd.z : d; fi = c2 ? ii.z : fi;
    bool c3 = (dd.w > d) || (dd.w == d && ii.w < fi);
    fi = c3 ? ii.w : fi;
    const float4 cp = S.pts[fi];
    if (t == 0) {
      int slot = (it & 63) * 3;
      S.chunk[slot + 0] = cp.x;
      S.chunk[slot + 1] = cp.y;
      S.chunk[slot + 2] = cp.z;
    }
    bv = -INFINITY;
    br = 0;
#pragma unroll
    for (int r = 0; r < 16; ++r) {
      float dnew = d2_exact(px[r], py[r], pz[r], cp.x, cp.y, cp.z);
      float nd = fminf(dist[r], dnew);
      dist[r] = nd;
      bool c = nd > bv;
      bv = c ? nd : bv;
      br = c ? r : br;
    }
  }
  __syncthreads();  // chunk holds centroids [960,1024)
  if (t < 192) {
    dstb[(NPOINT - 64) * 3 + t] = S.chunk[t];
    __threadfence();
  }
  __syncthreads();
  if (t == 0)
    __hip_atomic_store(&progress[b], NPOINT, __ATOMIC_RELEASE,
                       __HIP_MEMORY_SCOPE_AGENT);
}

// ---------------------------------------------------------------- MLP gemms
// W streamed from global/L2 (R1/R3-proven; LDS staging spilled in R2).
template <int K>
__device__ __forceinline__ void gemm_tile(const float* __restrict__ a0,
                                          const float* __restrict__ a1,
                                          const float* __restrict__ a2,
                                          const float* __restrict__ a3,
                                          const float* __restrict__ W,
                                          float acc[4][4]) {
  int k = 0;
  for (; k + 4 <= K; k += 4) {
    float4 A0 = *(const float4*)(a0 + k);
    float4 A1 = *(const float4*)(a1 + k);
    float4 A2 = *(const float4*)(a2 + k);
    float4 A3 = *(const float4*)(a3 + k);
#pragma unroll
    for (int kk = 0; kk < 4; ++kk) {
      float4 w = *(const float4*)(W + (size_t)(k + kk) * HID);
      float e0 = (&A0.x)[kk], e1 = (&A1.x)[kk], e2 = (&A2.x)[kk], e3 = (&A3.x)[kk];
      acc[0][0] += e0 * w.x; acc[0][1] += e0 * w.y; acc[0][2] += e0 * w.z; acc[0][3] += e0 * w.w;
      acc[1][0] += e1 * w.x; acc[1][1] += e1 * w.y; acc[1][2] += e1 * w.z; acc[1][3] += e1 * w.w;
      acc[2][0] += e2 * w.x; acc[2][1] += e2 * w.y; acc[2][2] += e2 * w.z; acc[2][3] += e2 * w.w;
      acc[3][0] += e3 * w.x; acc[3][1] += e3 * w.y; acc[3][2] += e3 * w.z; acc[3][3] += e3 * w.w;
    }
  }
  for (; k < K; ++k) {
    float4 w = *(const float4*)(W + (size_t)k * HID);
    float e0 = a0[k], e1 = a1[k], e2 = a2[k], e3 = a3[k];
    acc[0][0] += e0 * w.x; acc[0][1] += e0 * w.y; acc[0][2] += e0 * w.z; acc[0][3] += e0 * w.w;
    acc[1][0] += e1 * w.x; acc[1][1] += e1 * w.y; acc[1][2] += e1 * w.z; acc[1][3] += e1 * w.w;
    acc[2][0] += e2 * w.x; acc[2][1] += e2 * w.y; acc[2][2] += e2 * w.z; acc[2][3] += e2 * w.w;
    acc[3][0] += e3 * w.x; acc[3][1] += e3 * w.y; acc[3][2] += e3 * w.z; acc[3][3] += e3 * w.w;
  }
}

__device__ __forceinline__ void gemm_tile_corr(const float* __restrict__ a0,
                                               const float* __restrict__ a1,
                                               const float* __restrict__ a2,
                                               const float* __restrict__ a3,
                                               const float* __restrict__ W,
                                               const float* __restrict__ fm,
                                               float acc[4][4], float corr[4]) {
  for (int k = 0; k < HID; k += 4) {
    float4 A0 = *(const float4*)(a0 + k);
    float4 A1 = *(const float4*)(a1 + k);
    float4 A2 = *(const float4*)(a2 + k);
    float4 A3 = *(const float4*)(a3 + k);
    float4 FM = *(const float4*)(fm + k);
#pragma unroll
    for (int kk = 0; kk < 4; ++kk) {
      float4 w = *(const float4*)(W + (size_t)(k + kk) * HID);
      float e0 = (&A0.x)[kk], e1 = (&A1.x)[kk], e2 = (&A2.x)[kk], e3 = (&A3.x)[kk];
      float cf = (&FM.x)[kk];
      acc[0][0] += e0 * w.x; acc[0][1] += e0 * w.y; acc[0][2] += e0 * w.z; acc[0][3] += e0 * w.w;
      acc[1][0] += e1 * w.x; acc[1][1] += e1 * w.y; acc[1][2] += e1 * w.z; acc[1][3] += e1 * w.w;
      acc[2][0] += e2 * w.x; acc[2][1] += e2 * w.y; acc[2][2] += e2 * w.z; acc[2][3] += e2 * w.w;
      acc[3][0] += e3 * w.x; acc[3][1] += e3 * w.y; acc[3][2] += e3 * w.z; acc[3][3] += e3 * w.w;
      corr[0] += cf * w.x; corr[1] += cf * w.y; corr[2] += cf * w.z; corr[3] += cf * w.w;
    }
  }
}

// ---------------------------------------------------------------- consumer
__device__ void run_consumer(const float* __restrict__ xyz,
                             const float* __restrict__ feats,
                             const float* __restrict__ W1f,
                             const float* __restrict__ b1f,
                             const float* __restrict__ W2f,
                             const float* __restrict__ b2f,
                             const float* __restrict__ W1w,
                             const float* __restrict__ b1w,
                             const float* __restrict__ W2w,
                             const float* __restrict__ b2w,
                             const float* __restrict__ newxyz,
                             float* __restrict__ fout, int* progress,
                             int* ticket, ConsS& S) {
  const int t = threadIdx.x;
  const int wv = t >> 6;
  const int lane = t & 63;
  const float r2 = 0.0225f;  // np float32(RADIUS**2)

  while (true) {
    if (t == 0) S.tkS = atomicAdd(ticket, 1);
    __syncthreads();
    const int tk = S.tkS;
    if (tk >= NB * NPOINT) return;
    const int it = tk >> 3;
    const int b = tk & 7;
    const int g = b * NPOINT + it;

    // wait until centroid `it` of batch b is published
    if (t == 0) {
      while (__hip_atomic_load(&progress[b], __ATOMIC_RELAXED,
                               __HIP_MEMORY_SCOPE_AGENT) <= it)
        __builtin_amdgcn_s_sleep(32);
    }
    __syncthreads();
    {  // every thread acquires (orders its own subsequent loads)
      int pv = __hip_atomic_load(&progress[b], __ATOMIC_ACQUIRE,
                                 __HIP_MEMORY_SCOPE_AGENT);
      while (pv <= it) {
        __builtin_amdgcn_s_sleep(8);
        pv = __hip_atomic_load(&progress[b], __ATOMIC_ACQUIRE,
                               __HIP_MEMORY_SCOPE_AGENT);
      }
    }
    const float cx = newxyz[g * 3 + 0];
    const float cy = newxyz[g * 3 + 1];
    const float cz = newxyz[g * 3 + 2];

    // ---- knn: 4-wave scan, per-wave compaction, rank-select 32 smallest
    const float* src = xyz + (size_t)b * NPTS * 3;
    int cnt = 0;
    const int jb = wv * 1024;
    for (int j0 = jb; j0 < jb + 1024; j0 += 64) {
      const int p = j0 + lane;
      const float* pp = src + p * 3;
      float d2 = d2_exact(pp[0], pp[1], pp[2], cx, cy, cz);
      bool inr = (d2 <= r2);
      ull mask = __ballot(inr);
      if (inr) {
        int pos = cnt + __popcll(mask & ((1ull << lane) - 1ull));
        if (pos < CAPW)
          S.candseg[wv][pos] = ((ull)__float_as_uint(d2) << 32) | (unsigned)p;
      }
      cnt += __popcll(mask);
    }
    if (lane == 0) S.scnt[wv] = cnt < CAPW ? cnt : CAPW;
    __syncthreads();
    const int n0 = S.scnt[0], n1 = S.scnt[1], n2 = S.scnt[2], n3 = S.scnt[3];
    const int C = n0 + n1 + n2 + n3;
    {
      int off = (wv > 0 ? n0 : 0) + (wv > 1 ? n1 : 0) + (wv > 2 ? n2 : 0);
      int myn = S.scnt[wv];
      for (int i = lane; i < myn; i += 64) S.cand2[off + i] = S.candseg[wv][i];
    }
    __syncthreads();
    for (int tt = t; tt < C; tt += 256) {
      ull key = S.cand2[tt];
      int rank = 0;
      for (int u = 0; u < C; ++u) rank += (S.cand2[u] < key) ? 1 : 0;
      if (rank < NSAMPLE) S.sidx[rank] = (int)(key & 0xffffffffu);
    }
    if (C < NSAMPLE && wv == 0) {  // boundary fill: lowest-index outside pts
      const float* pp = src + lane * 3;
      float d2 = d2_exact(pp[0], pp[1], pp[2], cx, cy, cz);
      bool outr = !(d2 <= r2);
      ull mask = __ballot(outr);
      if (outr) {
        int pos = __popcll(mask & ((1ull << lane) - 1ull));
        if (pos < NSAMPLE - C) S.sidx[C + pos] = lane;
      }
    }
    __syncthreads();

    // ---- mlp (R3-proven structure)
    if (t < 32) {
      const float* pp = src + (size_t)S.sidx[t] * 3;
      S.fin[t][0] = pp[0] - cx;
      S.fin[t][1] = pp[1] - cy;
      S.fin[t][2] = pp[2] - cz;
      S.fin[t][67] = 0.f;
    }
    for (int e = t; e < 32 * FCH; e += 256) {
      int s = e >> 6;
      int c = e & 63;
      S.fin[s][3 + c] = feats[((size_t)b * NPTS + S.sidx[s]) * FCH + c];
    }
    __syncthreads();

    const int s0 = (t >> 5) * 4;
    const int c0 = (t & 31) * 4;
    float acc[4][4];

    // G1
    {
      float4 bv4 = *(const float4*)(b1f + c0);
#pragma unroll
      for (int i = 0; i < 4; ++i) { acc[i][0] = bv4.x; acc[i][1] = bv4.y; acc[i][2] = bv4.z; acc[i][3] = bv4.w; }
    }
    gemm_tile<67>(S.fin[s0], S.fin[s0 + 1], S.fin[s0 + 2], S.fin[s0 + 3],
                  W1f + c0, acc);
#pragma unroll
    for (int i = 0; i < 4; ++i)
#pragma unroll
      for (int j = 0; j < 4; ++j) S.bufA[s0 + i][c0 + j] = fmaxf(acc[i][j], 0.f);
    __syncthreads();

    // G2
    {
      float4 bv4 = *(const float4*)(b2f + c0);
#pragma unroll
      for (int i = 0; i < 4; ++i) { acc[i][0] = bv4.x; acc[i][1] = bv4.y; acc[i][2] = bv4.z; acc[i][3] = bv4.w; }
    }
    gemm_tile<128>(S.bufA[s0], S.bufA[s0 + 1], S.bufA[s0 + 2], S.bufA[s0 + 3],
                   W2f + c0, acc);
#pragma unroll
    for (int i = 0; i < 4; ++i)
#pragma unroll
      for (int j = 0; j < 4; ++j) S.fp[s0 + i][c0 + j] = fmaxf(acc[i][j], 0.f);
    __syncthreads();

    if (t < HID) {
      float s = 0.f;
#pragma unroll 8
      for (int i = 0; i < 32; ++i) s += S.fp[i][t];
      S.fm[t] = s * (1.0f / 32.0f);
    }
    __syncthreads();

    // G3: relu( fp@W1w[3:] + (b1w + dxyz@W1w[0:3]) - fm@W1w[3:] )
    float corr[4] = {0.f, 0.f, 0.f, 0.f};
    {
      float4 bv4 = *(const float4*)(b1w + c0);
      float4 w0 = *(const float4*)(W1w + 0 * HID + c0);
      float4 w1 = *(const float4*)(W1w + 1 * HID + c0);
      float4 w2 = *(const float4*)(W1w + 2 * HID + c0);
#pragma unroll
      for (int i = 0; i < 4; ++i) {
        float dx = S.fin[s0 + i][0], dy = S.fin[s0 + i][1], dz = S.fin[s0 + i][2];
        acc[i][0] = bv4.x + dx * w0.x + dy * w1.x + dz * w2.x;
        acc[i][1] = bv4.y + dx * w0.y + dy * w1.y + dz * w2.y;
        acc[i][2] = bv4.z + dx * w0.z + dy * w1.z + dz * w2.z;
        acc[i][3] = bv4.w + dx * w0.w + dy * w1.w + dz * w2.w;
      }
    }
    gemm_tile_corr(S.fp[s0], S.fp[s0 + 1], S.fp[s0 + 2], S.fp[s0 + 3],
                   W1w + 3 * HID + c0, S.fm, acc, corr);
    __syncthreads();
#pragma unroll
    for (int i = 0; i < 4; ++i)
#pragma unroll
      for (int j = 0; j < 4; ++j)
        S.bufA[s0 + i][c0 + j] = fmaxf(acc[i][j] - corr[j], 0.f);
    __syncthreads();

    // G4
    {
      float4 bv4 = *(const float4*)(b2w + c0);
#pragma unroll
      for (int i = 0; i < 4; ++i) { acc[i][0] = bv4.x; acc[i][1] = bv4.y; acc[i][2] = bv4.z; acc[i][3] = bv4.w; }
    }
    gemm_tile<128>(S.bufA[s0], S.bufA[s0 + 1], S.bufA[s0 + 2], S.bufA[s0 + 3],
                   W2w + c0, acc);
    {
      float part[4] = {0.f, 0.f, 0.f, 0.f};
#pragma unroll
      for (int i = 0; i < 4; ++i)
#pragma unroll
        for (int j = 0; j < 4; ++j) {
          float al = 1.0f / (1.0f + __expf(-acc[i][j]));
          part[j] += al * S.fp[s0 + i][c0 + j];
        }
      __syncthreads();  // fin dead -> reuse as 8xHID reduction buffer
      float* redp = &S.fin[0][0];
      redp[(t >> 5) * HID + c0 + 0] = part[0];
      redp[(t >> 5) * HID + c0 + 1] = part[1];
      redp[(t >> 5) * HID + c0 + 2] = part[2];
      redp[(t >> 5) * HID + c0 + 3] = part[3];
    }
    __syncthreads();
    if (t < HID) {
      float* redp = &S.fin[0][0];
      float s = 0.f;
#pragma unroll
      for (int w = 0; w < 8; ++w) s += redp[w * HID + t];
      fout[(size_t)g * HID + t] = s;
    }
    __syncthreads();  // LDS fully consumed before next ticket
  }
}

// ---------------------------------------------------------------- fused
__global__ __launch_bounds__(256, 2) void sa_fused_kernel(
    const float* __restrict__ xyz, const float* __restrict__ feats,
    const float* __restrict__ W1f, const float* __restrict__ b1f,
    const float* __restrict__ W2f, const float* __restrict__ b2f,
    const float* __restrict__ W1w, const float* __restrict__ b1w,
    const float* __restrict__ W2w, const float* __restrict__ b2w,
    float* __restrict__ newxyz, float* __restrict__ fout, int* ctrl) {
  __shared__ SMemU sm;
  int* progress = ctrl;      // [0..7]
  int* ticket = ctrl + 8;    // [8]
  if (blockIdx.x < NB) {
    run_fps(xyz, newxyz, progress, blockIdx.x, sm.p);
    __syncthreads();
  }
  run_consumer(xyz, feats, W1f, b1f, W2f, b2f, W1w, b1w, W2w, b2w, newxyz,
               fout, progress, ticket, sm.c);
}

extern "C" void kernel_launch(void* const* d_in, const int* in_sizes, int n_in,
                              void* d_out, int out_size, void* d_ws, size_t ws_size,
                              hipStream_t stream) {
  const float* xyz = (const float*)d_in[0];
  const float* feats = (const float*)d_in[1];
  const float* W1f = (const float*)d_in[2];
  const float* b1f = (const float*)d_in[3];
  const float* W2f = (const float*)d_in[4];
  const float* b2f = (const float*)d_in[5];
  const float* W1w = (const float*)d_in[6];
  const float* b1w = (const float*)d_in[7];
  const float* W2w = (const float*)d_in[8];
  const float* b2w = (const float*)d_in[9];

  float* newxyz = (float*)d_out;                          // (8,1024,3)
  float* fout = (float*)d_out + (size_t)NB * NPOINT * 3;  // (8,1024,128)
  int* ctrl = (int*)d_ws;  // progress[8] + ticket[1]

  hipMemsetAsync(ctrl, 0, 64, stream);
  // 8 producers + 248 consumers = 256 blocks <= 256 CUs: co-resident even at
  // 1 block/CU (LDS 66.4KB -> 2/CU by spec). No deadlock possible.
  sa_fused_kernel<<<256, 256, 0, stream>>>(xyz, feats, W1f, b1f, W2f, b2f,
                                           W1w, b1w, W2w, b2w, newxyz, fout,
                                           ctrl);
}